// Round 3
// baseline (1238.109 us; speedup 1.0000x reference)
//
#include <hip/hip_runtime.h>
#include <math.h>

#define NTOK  32768   // B*T
#define DDIM  2048
#define NEXP  64
#define TOPK  8
#define TPW   16      // tokens per wave
#define WPB   4       // waves per block
#define KC    128     // K-chunk staged in LDS (128*64 floats = 32 KB)
#define THR   2.5e-4f // contested-gap threshold (relative, ~100x fp32 err tail)

__global__ __launch_bounds__(256, 4) void router_kernel(
    const float* __restrict__ x, const float* __restrict__ w,
    float* __restrict__ out) {
  __shared__ float wlds[KC * NEXP];  // 32 KB

  const int tid  = threadIdx.x;
  const int lane = tid & 63;                                  // = expert id
  const int wave = __builtin_amdgcn_readfirstlane(tid >> 6);  // wave-uniform
  const int tok0 = blockIdx.x * (TPW * WPB) + wave * TPW;

  float acc[TPW];
#pragma unroll
  for (int t = 0; t < TPW; ++t) acc[t] = 0.0f;

  // ---------- pass 1: fp32 logits ----------
  for (int c = 0; c < DDIM / KC; ++c) {
    __syncthreads();
    const float4* src = (const float4*)(w + c * (KC * NEXP));
    float4* dst = (float4*)wlds;
#pragma unroll
    for (int i = 0; i < (KC * NEXP / 4) / 256; ++i)  // 8 float4 per thread
      dst[tid + i * 256] = src[tid + i * 256];
    __syncthreads();

    const int kbase = c * KC;
#pragma unroll 2
    for (int d4 = 0; d4 < KC / 4; ++d4) {
      const float w0 = wlds[(d4 * 4 + 0) * NEXP + lane];
      const float w1 = wlds[(d4 * 4 + 1) * NEXP + lane];
      const float w2 = wlds[(d4 * 4 + 2) * NEXP + lane];
      const float w3 = wlds[(d4 * 4 + 3) * NEXP + lane];
#pragma unroll
      for (int t = 0; t < TPW; ++t) {
        const float4 xv =
            *(const float4*)(x + (size_t)(tok0 + t) * DDIM + kbase + d4 * 4);
        acc[t] = fmaf(xv.x, w0, acc[t]);
        acc[t] = fmaf(xv.y, w1, acc[t]);
        acc[t] = fmaf(xv.z, w2, acc[t]);
        acc[t] = fmaf(xv.w, w3, acc[t]);
      }
    }
  }

  float* out_w = out;                          // (NTOK, 8) fp32 weights
  float* out_i = out + (size_t)NTOK * TOPK;    // (NTOK, 8) indices as float

#pragma unroll 1
  for (int t = 0; t < TPW; ++t) {
    const int tok = tok0 + t;
    const float v = acc[t];

    // fp32 softmax over 64 experts (one per lane)
    float m = v;
#pragma unroll
    for (int off = 32; off; off >>= 1) m = fmaxf(m, __shfl_xor(m, off));
    const float ex = __expf(v - m);
    float s = ex;
#pragma unroll
    for (int off = 32; off; off >>= 1) s += __shfl_xor(s, off);
    float pw = ex / s;

    // top-9 by prob (9th rank only for the gap check); tie -> lower index
    float selv[TOPK + 1];
    int   seli[TOPK + 1];
#pragma unroll
    for (int r = 0; r < TOPK + 1; ++r) {
      float bv = pw;
      int   bi = lane;
#pragma unroll
      for (int off = 32; off; off >>= 1) {
        const float ov = __shfl_xor(bv, off);
        const int   oi = __shfl_xor(bi, off);
        const bool take = (ov > bv) || (ov == bv && oi < bi);
        bv = take ? ov : bv;
        bi = take ? oi : bi;
      }
      selv[r] = bv;
      seli[r] = bi;
      if (lane == bi) pw = -__builtin_inff();
    }

    bool contested = false;
#pragma unroll
    for (int k = 0; k < TOPK; ++k)
      contested |= (selv[k] - selv[k + 1]) <= THR * selv[0];

    if (!contested) {
      // commit fp32 result
      const float mm = selv[0];
      float ssum = 0.0f;
#pragma unroll
      for (int k = 0; k < TOPK; ++k) ssum += __expf(selv[k] - mm);
      float myv = selv[0];
      int   myi = seli[0];
#pragma unroll
      for (int k = 1; k < TOPK; ++k)
        if (lane == k) { myv = selv[k]; myi = seli[k]; }
      if (lane < TOPK) {
        out_w[(size_t)tok * TOPK + lane] = __expf(myv - mm) / ssum;
        out_i[(size_t)tok * TOPK + lane] = (float)myi;
      }
    } else {
      // ---------- f64 recompute, bit-identical to the R2 (passing) path ----
      double a = 0.0;
      const float* xr = x + (size_t)tok * DDIM;
#pragma unroll 2
      for (int d4 = 0; d4 < DDIM / 4; ++d4) {
        const float4 xv = *(const float4*)(xr + d4 * 4);
        a = fma((double)xv.x, (double)w[(d4 * 4 + 0) * NEXP + lane], a);
        a = fma((double)xv.y, (double)w[(d4 * 4 + 1) * NEXP + lane], a);
        a = fma((double)xv.z, (double)w[(d4 * 4 + 2) * NEXP + lane], a);
        a = fma((double)xv.w, (double)w[(d4 * 4 + 3) * NEXP + lane], a);
      }
      double dm = a;
#pragma unroll
      for (int off = 32; off; off >>= 1) dm = fmax(dm, __shfl_xor(dm, off));
      const double dex = exp(a - dm);
      double ds = dex;
#pragma unroll
      for (int off = 32; off; off >>= 1) ds += __shfl_xor(ds, off);
      double dpv = dex / ds;

      double dselv[TOPK];
      int    dseli[TOPK];
#pragma unroll
      for (int r = 0; r < TOPK; ++r) {
        double bv = dpv;
        int    bi = lane;
#pragma unroll
        for (int off = 32; off; off >>= 1) {
          const double ov = __shfl_xor(bv, off);
          const int    oi = __shfl_xor(bi, off);
          const bool take = (ov > bv) || (ov == bv && oi < bi);
          bv = take ? ov : bv;
          bi = take ? oi : bi;
        }
        dselv[r] = bv;
        dseli[r] = bi;
        if (lane == bi) dpv = -1.0e300;
      }
      const double dmm = dselv[0];
      double dssum = 0.0;
#pragma unroll
      for (int k = 0; k < TOPK; ++k) dssum += exp(dselv[k] - dmm);
      double myv = dselv[0];
      int    myi = dseli[0];
#pragma unroll
      for (int k = 1; k < TOPK; ++k)
        if (lane == k) { myv = dselv[k]; myi = dseli[k]; }
      if (lane < TOPK) {
        out_w[(size_t)tok * TOPK + lane] = (float)(exp(myv - dmm) / dssum);
        out_i[(size_t)tok * TOPK + lane] = (float)myi;
      }
    }
  }
}

extern "C" void kernel_launch(void* const* d_in, const int* in_sizes, int n_in,
                              void* d_out, int out_size, void* d_ws, size_t ws_size,
                              hipStream_t stream) {
  const float* x = (const float*)d_in[0];
  const float* w = (const float*)d_in[1];
  router_kernel<<<dim3(NTOK / (TPW * WPB)), dim3(256), 0, stream>>>(
      x, w, (float*)d_out);
}

// Round 4
// 778.821 us; speedup vs baseline: 1.5897x; 1.5897x over previous
//
#include <hip/hip_runtime.h>
#include <math.h>

#define NTOK  32768   // B*T
#define DDIM  2048
#define NEXP  64
#define TOPK  8
#define TPW   8       // tokens per wave (main)
#define WPB   4       // waves per block
#define KC    128     // K-chunk staged in LDS (128*64 floats = 32 KB)
#define GAP_THR  1e-4f   // absolute logit-gap contested threshold (~60x fp32 err)
#define LIST_CAP 32000

__global__ void init_ws(int* cnt) { if (threadIdx.x == 0) cnt[0] = 0; }

// ---------------- main pass: fp32 logits + top-9 + contested flag ----------
__global__ __launch_bounds__(256, 4) void router_main(
    const float* __restrict__ x, const float* __restrict__ w,
    float* __restrict__ out, int* __restrict__ cnt, int* __restrict__ list) {
  __shared__ float wlds[KC * NEXP];  // 32 KB

  const int tid  = threadIdx.x;
  const int lane = tid & 63;                                  // = expert id
  const int wave = __builtin_amdgcn_readfirstlane(tid >> 6);  // wave-uniform
  const int tok0 = blockIdx.x * (TPW * WPB) + wave * TPW;

  float acc[TPW];
#pragma unroll
  for (int t = 0; t < TPW; ++t) acc[t] = 0.0f;

  for (int c = 0; c < DDIM / KC; ++c) {
    __syncthreads();
    const float4* src = (const float4*)(w + c * (KC * NEXP));
    float4* dst = (float4*)wlds;
#pragma unroll
    for (int i = 0; i < (KC * NEXP / 4) / 256; ++i)  // 8 float4 / thread
      dst[tid + i * 256] = src[tid + i * 256];
    __syncthreads();

    const int kbase = c * KC;
#pragma unroll 2
    for (int d4 = 0; d4 < KC / 4; ++d4) {
      const float w0 = wlds[(d4 * 4 + 0) * NEXP + lane];
      const float w1 = wlds[(d4 * 4 + 1) * NEXP + lane];
      const float w2 = wlds[(d4 * 4 + 2) * NEXP + lane];
      const float w3 = wlds[(d4 * 4 + 3) * NEXP + lane];
#pragma unroll
      for (int t = 0; t < TPW; ++t) {
        // wave-uniform address -> scalar (s_load) path
        const float4 xv =
            *(const float4*)(x + (size_t)(tok0 + t) * DDIM + kbase + d4 * 4);
        acc[t] = fmaf(xv.x, w0, acc[t]);
        acc[t] = fmaf(xv.y, w1, acc[t]);
        acc[t] = fmaf(xv.z, w2, acc[t]);
        acc[t] = fmaf(xv.w, w3, acc[t]);
      }
    }
  }

  float* out_w = out;                          // (NTOK, 8) weights
  float* out_i = out + (size_t)NTOK * TOPK;    // (NTOK, 8) indices as float

#pragma unroll 1
  for (int t = 0; t < TPW; ++t) {
    const int tok = tok0 + t;
    const float v = acc[t];  // fp32 logit for expert `lane`

    // softmax over 64 experts
    float m = v;
#pragma unroll
    for (int off = 32; off; off >>= 1) m = fmaxf(m, __shfl_xor(m, off));
    const float ex = __expf(v - m);
    float s = ex;
#pragma unroll
    for (int off = 32; off; off >>= 1) s += __shfl_xor(s, off);
    float pw = ex / s;   // prob (selection key, knocked out as picked)
    float lw = v;        // logit (rides along for the gap check)
    int   ii = lane;

    // top-9; tie -> lower index (rank 9 only feeds the gap check)
    float selp[TOPK + 1];
    float sell[TOPK + 1];
    int   seli[TOPK + 1];
#pragma unroll
    for (int r = 0; r < TOPK + 1; ++r) {
      float bp = pw; float bl = lw; int bi = ii;
#pragma unroll
      for (int off = 32; off; off >>= 1) {
        const float op = __shfl_xor(bp, off);
        const float ol = __shfl_xor(bl, off);
        const int   oi = __shfl_xor(bi, off);
        const bool take = (op > bp) || (op == bp && oi < bi);
        bp = take ? op : bp;
        bl = take ? ol : bl;
        bi = take ? oi : bi;
      }
      selp[r] = bp; sell[r] = bl; seli[r] = bi;
      if (lane == bi) pw = -__builtin_inff();
    }

    bool contested = false;
#pragma unroll
    for (int k = 0; k < TOPK; ++k)
      contested |= (sell[k] - sell[k + 1]) <= GAP_THR;

    // commit fp32 result for every token (contested ones overwritten later)
    const float mm = selp[0];
    float ssum = 0.0f;
#pragma unroll
    for (int k = 0; k < TOPK; ++k) ssum += __expf(selp[k] - mm);
    float myv = selp[0];
    int   myi = seli[0];
#pragma unroll
    for (int k = 1; k < TOPK; ++k)
      if (lane == k) { myv = selp[k]; myi = seli[k]; }
    if (lane < TOPK) {
      out_w[(size_t)tok * TOPK + lane] = __expf(myv - mm) / ssum;
      out_i[(size_t)tok * TOPK + lane] = (float)myi;
    }

    if (contested && lane == 0) {
      const int idx = atomicAdd(cnt, 1);
      if (idx < LIST_CAP) list[idx] = tok;
    }
  }
}

// ---------------- fix pass: f64 recompute of contested tokens --------------
__global__ __launch_bounds__(256, 1) void router_fix(
    const float* __restrict__ x, const float* __restrict__ w,
    float* __restrict__ out, const int* __restrict__ cnt,
    const int* __restrict__ list) {
  const int lane = threadIdx.x & 63;
  const int wave = threadIdx.x >> 6;
  const int gw   = blockIdx.x * 4 + wave;
  const int NW   = gridDim.x * 4;

  int n = cnt[0];
  if (n > LIST_CAP) n = LIST_CAP;

  float* out_w = out;
  float* out_i = out + (size_t)NTOK * TOPK;

  for (int i = gw; i < n; i += NW) {
    const int tok = list[i];
    const float* xr = x + (size_t)tok * DDIM;
    double a0 = 0.0, a1 = 0.0, a2 = 0.0, a3 = 0.0;  // 4 indep chains
#pragma unroll 4
    for (int d4 = 0; d4 < DDIM / 4; ++d4) {
      const float4 xv = *(const float4*)(xr + d4 * 4);
      const int r = d4 * 4;
      a0 = fma((double)xv.x, (double)w[(r + 0) * NEXP + lane], a0);
      a1 = fma((double)xv.y, (double)w[(r + 1) * NEXP + lane], a1);
      a2 = fma((double)xv.z, (double)w[(r + 2) * NEXP + lane], a2);
      a3 = fma((double)xv.w, (double)w[(r + 3) * NEXP + lane], a3);
    }
    const double a = (a0 + a1) + (a2 + a3);

    double dm = a;
#pragma unroll
    for (int off = 32; off; off >>= 1) dm = fmax(dm, __shfl_xor(dm, off));
    const double dex = exp(a - dm);
    double ds = dex;
#pragma unroll
    for (int off = 32; off; off >>= 1) ds += __shfl_xor(ds, off);
    double dpv = dex / ds;

    double dselv[TOPK];
    int    dseli[TOPK];
#pragma unroll
    for (int r = 0; r < TOPK; ++r) {
      double bv = dpv;
      int    bi = lane;
#pragma unroll
      for (int off = 32; off; off >>= 1) {
        const double ov = __shfl_xor(bv, off);
        const int    oi = __shfl_xor(bi, off);
        const bool take = (ov > bv) || (ov == bv && oi < bi);
        bv = take ? ov : bv;
        bi = take ? oi : bi;
      }
      dselv[r] = bv;
      dseli[r] = bi;
      if (lane == bi) dpv = -1.0e300;
    }
    const double dmm = dselv[0];
    double dssum = 0.0;
#pragma unroll
    for (int k = 0; k < TOPK; ++k) dssum += exp(dselv[k] - dmm);
    double myv = dselv[0];
    int    myi = dseli[0];
#pragma unroll
    for (int k = 1; k < TOPK; ++k)
      if (lane == k) { myv = dselv[k]; myi = dseli[k]; }
    if (lane < TOPK) {
      out_w[(size_t)tok * TOPK + lane] = (float)(exp(myv - dmm) / dssum);
      out_i[(size_t)tok * TOPK + lane] = (float)myi;
    }
  }
}

extern "C" void kernel_launch(void* const* d_in, const int* in_sizes, int n_in,
                              void* d_out, int out_size, void* d_ws, size_t ws_size,
                              hipStream_t stream) {
  const float* x = (const float*)d_in[0];
  const float* w = (const float*)d_in[1];
  int* cnt  = (int*)d_ws;
  int* list = (int*)d_ws + 4;

  init_ws<<<dim3(1), dim3(64), 0, stream>>>(cnt);
  router_main<<<dim3(NTOK / (TPW * WPB)), dim3(256), 0, stream>>>(
      x, w, (float*)d_out, cnt, list);
  router_fix<<<dim3(256), dim3(256), 0, stream>>>(
      x, w, (float*)d_out, cnt, list);
}

// Round 5
// 603.324 us; speedup vs baseline: 2.0521x; 1.2909x over previous
//
#include <hip/hip_runtime.h>
#include <math.h>

#define NTOK  32768   // B*T
#define DDIM  2048
#define NEXP  64
#define TOPK  8
#define TPW   8       // tokens per wave (main)
#define WPB   4       // waves per block
#define KC    128     // K-chunk: W 128x64 floats (32 KB) + x 32x128 (16 KB)
#define GAP_THR  1e-4f   // absolute logit-gap contested threshold
#define LIST_CAP 32000

__global__ void init_ws(int* cnt) { if (threadIdx.x == 0) cnt[0] = 0; }

// ---------------- main pass: fp32 logits + top-9 + contested flag ----------
// x flows global -> (vector loads) -> LDS tile -> ds_read_b128 broadcast.
// NEVER let x become a scalar s_load: s_load shares lgkmcnt with ds_read and
// serialized the whole K-loop in R2-R4 (570 cy/iter vs 64 cy VALU floor).
__global__ __launch_bounds__(256, 3) void router_main(
    const float* __restrict__ x, const float* __restrict__ w,
    float* __restrict__ out, int* __restrict__ cnt, int* __restrict__ list) {
  __shared__ float wlds[KC * NEXP];       // 32 KB, W chunk, layout [d][e]
  __shared__ float xl[TPW * WPB * KC];    // 16 KB, x tile, layout [tok][d]

  const int tid  = threadIdx.x;
  const int lane = tid & 63;              // = expert id
  const int wave = tid >> 6;
  const int tok0 = blockIdx.x * (TPW * WPB) + wave * TPW;

  float acc[TPW];
#pragma unroll
  for (int t = 0; t < TPW; ++t) acc[t] = 0.0f;

  for (int c = 0; c < DDIM / KC; ++c) {
    __syncthreads();
    // stage W chunk: 2048 float4, 256 threads -> 8 each (coalesced)
    {
      const float4* src = (const float4*)(w + c * (KC * NEXP));
      float4* dst = (float4*)wlds;
#pragma unroll
      for (int i = 0; i < 8; ++i)
        dst[i * 256 + tid] = src[i * 256 + tid];
    }
    // stage x tile: each wave stages its own 8 rows x 128 cols = 256 float4
    {
      float4* xd = (float4*)xl;
#pragma unroll
      for (int i = 0; i < 4; ++i) {
        const int n   = i * 64 + lane;   // float4 index within wave tile
        const int row = n >> 5;          // token within wave (32 float4/row)
        const int col = n & 31;
        const float4 v = *(const float4*)(
            x + (size_t)(tok0 + row) * DDIM + c * KC + col * 4);
        xd[wave * 256 + n] = v;
      }
    }
    __syncthreads();

    const float4* xt = (const float4*)xl;
#pragma unroll 2
    for (int d4 = 0; d4 < KC / 4; ++d4) {
      // lane e reads column e of 4 consecutive K rows; 2-way alias = free
      const float w0 = wlds[(d4 * 4 + 0) * NEXP + lane];
      const float w1 = wlds[(d4 * 4 + 1) * NEXP + lane];
      const float w2 = wlds[(d4 * 4 + 2) * NEXP + lane];
      const float w3 = wlds[(d4 * 4 + 3) * NEXP + lane];
#pragma unroll
      for (int t = 0; t < TPW; ++t) {
        // wave-uniform LDS address -> ds_read_b128 broadcast, conflict-free
        const float4 xv = xt[(wave * TPW + t) * (KC / 4) + d4];
        acc[t] = fmaf(xv.x, w0, acc[t]);
        acc[t] = fmaf(xv.y, w1, acc[t]);
        acc[t] = fmaf(xv.z, w2, acc[t]);
        acc[t] = fmaf(xv.w, w3, acc[t]);
      }
    }
  }

  float* out_w = out;                          // (NTOK, 8) weights
  float* out_i = out + (size_t)NTOK * TOPK;    // (NTOK, 8) indices as float

#pragma unroll 1
  for (int t = 0; t < TPW; ++t) {
    const int tok = tok0 + t;
    const float v = acc[t];  // fp32 logit for expert `lane`

    // softmax over 64 experts
    float m = v;
#pragma unroll
    for (int off = 32; off; off >>= 1) m = fmaxf(m, __shfl_xor(m, off));
    const float ex = __expf(v - m);
    float s = ex;
#pragma unroll
    for (int off = 32; off; off >>= 1) s += __shfl_xor(s, off);
    float pw = ex / s;   // prob (selection key, knocked out as picked)
    float lw = v;        // logit (rides along for the gap check)
    int   ii = lane;

    // top-9; tie -> lower index (rank 9 only feeds the gap check)
    float selp[TOPK + 1];
    float sell[TOPK + 1];
    int   seli[TOPK + 1];
#pragma unroll
    for (int r = 0; r < TOPK + 1; ++r) {
      float bp = pw; float bl = lw; int bi = ii;
#pragma unroll
      for (int off = 32; off; off >>= 1) {
        const float op = __shfl_xor(bp, off);
        const float ol = __shfl_xor(bl, off);
        const int   oi = __shfl_xor(bi, off);
        const bool take = (op > bp) || (op == bp && oi < bi);
        bp = take ? op : bp;
        bl = take ? ol : bl;
        bi = take ? oi : bi;
      }
      selp[r] = bp; sell[r] = bl; seli[r] = bi;
      if (lane == bi) pw = -__builtin_inff();
    }

    bool contested = false;
#pragma unroll
    for (int k = 0; k < TOPK; ++k)
      contested |= (sell[k] - sell[k + 1]) <= GAP_THR;

    // commit fp32 result for every token (contested ones overwritten later)
    const float mm = selp[0];
    float ssum = 0.0f;
#pragma unroll
    for (int k = 0; k < TOPK; ++k) ssum += __expf(selp[k] - mm);
    float myv = selp[0];
    int   myi = seli[0];
#pragma unroll
    for (int k = 1; k < TOPK; ++k)
      if (lane == k) { myv = selp[k]; myi = seli[k]; }
    if (lane < TOPK) {
      out_w[(size_t)tok * TOPK + lane] = __expf(myv - mm) / ssum;
      out_i[(size_t)tok * TOPK + lane] = (float)myi;
    }

    if (contested && lane == 0) {
      const int idx = atomicAdd(cnt, 1);
      if (idx < LIST_CAP) list[idx] = tok;
    }
  }
}

// ---------------- fix pass: f64 recompute of contested tokens --------------
__global__ __launch_bounds__(256, 1) void router_fix(
    const float* __restrict__ x, const float* __restrict__ w,
    float* __restrict__ out, const int* __restrict__ cnt,
    const int* __restrict__ list) {
  const int lane = threadIdx.x & 63;
  const int wave = threadIdx.x >> 6;
  const int gw   = blockIdx.x * 4 + wave;
  const int NW   = gridDim.x * 4;

  int n = cnt[0];
  if (n > LIST_CAP) n = LIST_CAP;

  float* out_w = out;
  float* out_i = out + (size_t)NTOK * TOPK;

  for (int i = gw; i < n; i += NW) {
    const int tok = list[i];
    const float* xr = x + (size_t)tok * DDIM;
    double a0 = 0.0, a1 = 0.0, a2 = 0.0, a3 = 0.0;  // 4 indep chains
#pragma unroll 4
    for (int d4 = 0; d4 < DDIM / 4; ++d4) {
      const float4 xv = *(const float4*)(xr + d4 * 4);
      const int r = d4 * 4;
      a0 = fma((double)xv.x, (double)w[(r + 0) * NEXP + lane], a0);
      a1 = fma((double)xv.y, (double)w[(r + 1) * NEXP + lane], a1);
      a2 = fma((double)xv.z, (double)w[(r + 2) * NEXP + lane], a2);
      a3 = fma((double)xv.w, (double)w[(r + 3) * NEXP + lane], a3);
    }
    const double a = (a0 + a1) + (a2 + a3);

    double dm = a;
#pragma unroll
    for (int off = 32; off; off >>= 1) dm = fmax(dm, __shfl_xor(dm, off));
    const double dex = exp(a - dm);
    double ds = dex;
#pragma unroll
    for (int off = 32; off; off >>= 1) ds += __shfl_xor(ds, off);
    double dpv = dex / ds;

    double dselv[TOPK];
    int    dseli[TOPK];
#pragma unroll
    for (int r = 0; r < TOPK; ++r) {
      double bv = dpv;
      int    bi = lane;
#pragma unroll
      for (int off = 32; off; off >>= 1) {
        const double ov = __shfl_xor(bv, off);
        const int    oi = __shfl_xor(bi, off);
        const bool take = (ov > bv) || (ov == bv && oi < bi);
        bv = take ? ov : bv;
        bi = take ? oi : bi;
      }
      dselv[r] = bv;
      dseli[r] = bi;
      if (lane == bi) dpv = -1.0e300;
    }
    const double dmm = dselv[0];
    double dssum = 0.0;
#pragma unroll
    for (int k = 0; k < TOPK; ++k) dssum += exp(dselv[k] - dmm);
    double myv = dselv[0];
    int    myi = dseli[0];
#pragma unroll
    for (int k = 1; k < TOPK; ++k)
      if (lane == k) { myv = dselv[k]; myi = dseli[k]; }
    if (lane < TOPK) {
      out_w[(size_t)tok * TOPK + lane] = (float)(exp(myv - dmm) / dssum);
      out_i[(size_t)tok * TOPK + lane] = (float)myi;
    }
  }
}

extern "C" void kernel_launch(void* const* d_in, const int* in_sizes, int n_in,
                              void* d_out, int out_size, void* d_ws, size_t ws_size,
                              hipStream_t stream) {
  const float* x = (const float*)d_in[0];
  const float* w = (const float*)d_in[1];
  int* cnt  = (int*)d_ws;
  int* list = (int*)d_ws + 4;

  init_ws<<<dim3(1), dim3(64), 0, stream>>>(cnt);
  router_main<<<dim3(NTOK / (TPW * WPB)), dim3(256), 0, stream>>>(
      x, w, (float*)d_out, cnt, list);
  router_fix<<<dim3(256), dim3(256), 0, stream>>>(
      x, w, (float*)d_out, cnt, list);
}